// Round 7
// baseline (53.486 us; speedup 1.0000x reference)
//
#include <hip/hip_runtime.h>
#include <hip/hip_bf16.h>

#define DDIM   256   // K (feature dim)
#define BROWS  512   // block output rows (8 waves x 64 rows)
#define BCOLS   32   // B tile columns
#define NTILES   8   // B tiles per block -> 256 cols per chunk

typedef float f32x4 __attribute__((ext_vector_type(4)));

// pack 4 f32 -> 4 fp8 e4m3 bytes (little-endian order a0..a3)
__device__ __forceinline__ unsigned int pack4_fp8(float a0, float a1, float a2, float a3) {
  int v = __builtin_amdgcn_cvt_pk_fp8_f32(a0, a1, 0, false);   // bytes 0,1
  v = __builtin_amdgcn_cvt_pk_fp8_f32(a2, a3, v, true);        // bytes 2,3
  return (unsigned int)v;
}

// ---- prep: one wave per row; writes UNIT-NORM fp8 rows + exact f32 diag ----
__global__ __launch_bounds__(256) void prep_kernel(
    const float* __restrict__ q, const float* __restrict__ r,
    unsigned char* __restrict__ qf8, unsigned char* __restrict__ rf8,
    float* __restrict__ pos, float* __restrict__ row_sum) {
  int lane = threadIdx.x & 63, wave = threadIdx.x >> 6;
  int row = blockIdx.x * 4 + wave;
  size_t base = (size_t)row * DDIM + lane * 4;
  float4 qv = *(const float4*)(q + base);
  float4 rv = *(const float4*)(r + base);
  float qq = qv.x*qv.x + qv.y*qv.y + qv.z*qv.z + qv.w*qv.w;
  float rr = rv.x*rv.x + rv.y*rv.y + rv.z*rv.z + rv.w*rv.w;
  float qr = qv.x*rv.x + qv.y*rv.y + qv.z*rv.z + qv.w*rv.w;
  #pragma unroll
  for (int m = 1; m < 64; m <<= 1) {   // butterfly: every lane gets the sums
    qq += __shfl_xor(qq, m);
    rr += __shfl_xor(rr, m);
    qr += __shfl_xor(qr, m);
  }
  float iq = 1.0f / sqrtf(qq);
  float ir = 1.0f / sqrtf(rr);
  // unit-norm elements ~|x|/16 in [1e-3, 0.3]: inside e4m3 range (subnormals
  // to 2^-9, max 448); values below ~1e-3 contribute negligibly to the dot.
  unsigned int qp = pack4_fp8(qv.x*iq, qv.y*iq, qv.z*iq, qv.w*iq);
  unsigned int rp = pack4_fp8(rv.x*ir, rv.y*ir, rv.z*ir, rv.w*ir);
  *(unsigned int*)(qf8 + base) = qp;
  *(unsigned int*)(rf8 + base) = rp;
  if (lane == 0) {
    pos[row] = qr * iq * ir;   // exact f32 diagonal from raw inputs
    row_sum[row] = 0.0f;
  }
}

// stage one 32-col x 256-K fp8 B tile (8 KB) into LDS, async, swizzled.
// LDS layout: byte(col, koff) = col*256 + (koff ^ ((col&7)<<4)).
// global_load_lds writes linearly (dst = base + tid*16), so the swizzle is
// applied to the SOURCE address (rule 21); XOR bits [6:4] keep 16B alignment.
__device__ __forceinline__ void stage_tile(unsigned char* dst,
                                           const unsigned char* src_base,
                                           int col0, int tid) {
  const char* gb = (const char*)src_base + (size_t)col0 * 256;
  int cc = tid >> 4;                    // tile-local col 0..31
  int w  = (tid & 15) << 4;             // 16B block within the 256B row
  int src = cc * 256 + (w ^ ((cc & 7) << 4));
  __builtin_amdgcn_global_load_lds(
      (const __attribute__((address_space(1))) void*)(gb + src),
      (__attribute__((address_space(3))) void*)(dst + tid * 16),
      16, 0, 0);
}

// one 512x32 tile in TWO sequential 16-col passes. A (fp8) from resident
// registers: 4 row-frags x 8 K-slices x 8B = 64 VGPR/wave. B from LDS via
// b64 reads (8B/lane), bank-uniform thanks to the (col&7)<<4 XOR.
__device__ __forceinline__ void compute_tile(
    const unsigned char* Bt, const long (&av)[4][8], float (&rs)[16],
    int g, int c) {
  const char* Bb = (const char*)Bt;
  #pragma unroll 1
  for (int half = 0; half < 2; ++half) {
    int cc = half * 16 + c;
    const char* colp = Bb + (size_t)cc * 256;
    int swz = (cc & 7) << 4;
    f32x4 acc[4];
    const f32x4 zero = {0.f, 0.f, 0.f, 0.f};
    #pragma unroll
    for (int m = 0; m < 4; ++m) acc[m] = zero;
    #pragma unroll
    for (int ks = 0; ks < 8; ++ks) {
      long bv = *(const long*)(colp + ((ks * 32 + g * 8) ^ swz));
      #pragma unroll
      for (int m = 0; m < 4; ++m)
        acc[m] = __builtin_amdgcn_mfma_f32_16x16x32_fp8_fp8(av[m][ks], bv,
                                                            acc[m], 0, 0, 0);
    }
    // unit-norm inputs: score = acc. C layout (dtype-independent, validated):
    // col = cc, row = m*16 + g*4 + j
    #pragma unroll
    for (int m = 0; m < 4; ++m)
      #pragma unroll
      for (int j = 0; j < 4; ++j)
        rs[m * 4 + j] += __expf(acc[m][j]);
  }
}

// 512 threads = 8 waves, each owning 64 rows. launch_bounds(512,4) caps the
// allocator at 128 VGPR — and the fp8 working set (~111) actually FITS, so
// the A fragments stay resident (bf16 needed 128 regs for av alone, which
// forced per-tile L2 re-reads of the whole A block: the R4-R6 bottleneck).
// 2 blocks/CU (16 waves, 4/SIMD) overlap barrier drains across blocks.
__global__ __launch_bounds__(512, 4) void gemm_lse_kernel(
    const unsigned char* __restrict__ qf8, const unsigned char* __restrict__ rf8,
    float* __restrict__ row_sum) {
  __shared__ __attribute__((aligned(16))) unsigned char Bl[2][BCOLS * DDIM]; // 2 x 8 KB

  const int tid  = threadIdx.x;
  const int lane = tid & 63;
  const int wid  = tid >> 6;
  const int g = lane >> 4, c = lane & 15;
  const int row0  = blockIdx.x * BROWS;
  const int col00 = blockIdx.y * (NTILES * BCOLS);

  // issue stage of tile 0 first; latency hides under the A-register loads
  stage_tile(&Bl[0][0], rf8, col00, tid);

  // A fragments -> registers (4 row-frags x 8 K-slices = 64 VGPR), read once
  long av[4][8];
  const char* Ab = (const char*)qf8;
  #pragma unroll
  for (int m = 0; m < 4; ++m) {
    size_t rb = (size_t)(row0 + wid * 64 + m * 16 + c) * 256;
    #pragma unroll
    for (int ks = 0; ks < 8; ++ks) {
      av[m][ks] = *(const long*)(Ab + rb + ks * 32 + g * 8);
      asm volatile("" : "+v"(av[m][ks]));   // pin: keep resident
    }
  }

  float rs[16];
  #pragma unroll
  for (int k = 0; k < 16; ++k) rs[k] = 0.0f;

  __syncthreads();   // tile 0 resident

  // 2-phase pipeline: issue stage(t+1) BEFORE compute(t); the single
  // __syncthreads per tile drains vmcnt AFTER compute so in-flight loads
  // hide under MFMA. Manual x2 unroll keeps buffer indices compile-time.
  for (int t = 0; t < NTILES; t += 2) {
    if (t + 1 < NTILES)
      stage_tile(&Bl[1][0], rf8, col00 + (t + 1) * BCOLS, tid);
    compute_tile(&Bl[0][0], av, rs, g, c);
    __syncthreads();

    if (t + 2 < NTILES)
      stage_tile(&Bl[0][0], rf8, col00 + (t + 2) * BCOLS, tid);
    compute_tile(&Bl[1][0], av, rs, g, c);
    __syncthreads();
  }

  // reduce the 16 column-lanes holding the same row, one atomic per row
  #pragma unroll
  for (int k = 0; k < 16; ++k) {
    float v = rs[k];
    v += __shfl_xor(v, 1);
    v += __shfl_xor(v, 2);
    v += __shfl_xor(v, 4);
    v += __shfl_xor(v, 8);
    if (c == 0) {
      int row = row0 + wid * 64 + (k >> 2) * 16 + g * 4 + (k & 3);
      atomicAdd(&row_sum[row], v);
    }
  }
}

__global__ __launch_bounds__(256) void finalize_kernel(
    const float* __restrict__ row_sum, const float* __restrict__ pos,
    float* __restrict__ out, int n) {
  int t = threadIdx.x;
  float s = 0.f;
  #pragma unroll 4
  for (int i = t; i < n; i += 256) s += __logf(row_sum[i]) - pos[i];
  #pragma unroll
  for (int m = 1; m < 64; m <<= 1) s += __shfl_xor(s, m);
  __shared__ float red[4];
  if ((t & 63) == 0) red[t >> 6] = s;
  __syncthreads();
  if (t == 0) out[0] = red[0] + red[1] + red[2] + red[3];  // -loss = sum(lse - pos)
}

extern "C" void kernel_launch(void* const* d_in, const int* in_sizes, int n_in,
                              void* d_out, int out_size, void* d_ws, size_t ws_size,
                              hipStream_t stream) {
  const float* q = (const float*)d_in[0];
  const float* r = (const float*)d_in[1];
  int n = in_sizes[0] / DDIM;  // 8192

  char* w = (char*)d_ws;
  size_t f8Bytes = (size_t)n * DDIM;
  unsigned char* qf8 = (unsigned char*)w;
  unsigned char* rf8 = (unsigned char*)(w + f8Bytes);
  float* pos     = (float*)(w + 2 * f8Bytes);
  float* row_sum = pos + n;

  prep_kernel<<<n / 4, 256, 0, stream>>>(q, r, qf8, rf8, pos, row_sum);

  dim3 grid(n / BROWS, n / (NTILES * BCOLS));   // 16 x 32 = 512 blocks (2/CU)
  gemm_lse_kernel<<<grid, 512, 0, stream>>>(qf8, rf8, row_sum);

  finalize_kernel<<<1, 256, 0, stream>>>(row_sum, pos, (float*)d_out, n);
}

// Round 8
// 53.386 us; speedup vs baseline: 1.0019x; 1.0019x over previous
//
#include <hip/hip_runtime.h>
#include <hip/hip_bf16.h>

#define DDIM   256   // K (feature dim)
#define BROWS  256   // block output rows (8 waves x 32 rows)
#define BCOLS  128   // B tile columns
#define NTILES   4   // B tiles per block -> 512 cols per chunk

typedef float f32x4 __attribute__((ext_vector_type(4)));

// pack 4 f32 -> 4 fp8 e4m3 bytes
__device__ __forceinline__ unsigned int pack4_fp8(float a0, float a1, float a2, float a3) {
  int v = __builtin_amdgcn_cvt_pk_fp8_f32(a0, a1, 0, false);   // bytes 0,1
  v = __builtin_amdgcn_cvt_pk_fp8_f32(a2, a3, v, true);        // bytes 2,3
  return (unsigned int)v;
}

// ---- prep: one wave per row; writes UNIT-NORM fp8 rows + exact f32 diag ----
__global__ __launch_bounds__(256) void prep_kernel(
    const float* __restrict__ q, const float* __restrict__ r,
    unsigned char* __restrict__ qf8, unsigned char* __restrict__ rf8,
    float* __restrict__ pos, float* __restrict__ row_sum) {
  int lane = threadIdx.x & 63, wave = threadIdx.x >> 6;
  int row = blockIdx.x * 4 + wave;
  size_t base = (size_t)row * DDIM + lane * 4;
  float4 qv = *(const float4*)(q + base);
  float4 rv = *(const float4*)(r + base);
  float qq = qv.x*qv.x + qv.y*qv.y + qv.z*qv.z + qv.w*qv.w;
  float rr = rv.x*rv.x + rv.y*rv.y + rv.z*rv.z + rv.w*rv.w;
  float qr = qv.x*rv.x + qv.y*rv.y + qv.z*rv.z + qv.w*rv.w;
  #pragma unroll
  for (int m = 1; m < 64; m <<= 1) {
    qq += __shfl_xor(qq, m);
    rr += __shfl_xor(rr, m);
    qr += __shfl_xor(qr, m);
  }
  float iq = 1.0f / sqrtf(qq);
  float ir = 1.0f / sqrtf(rr);
  unsigned int qp = pack4_fp8(qv.x*iq, qv.y*iq, qv.z*iq, qv.w*iq);
  unsigned int rp = pack4_fp8(rv.x*ir, rv.y*ir, rv.z*ir, rv.w*ir);
  *(unsigned int*)(qf8 + base) = qp;
  *(unsigned int*)(rf8 + base) = rp;
  if (lane == 0) {
    pos[row] = qr * iq * ir;   // exact f32 diagonal from raw inputs
    row_sum[row] = 0.0f;
  }
}

// stage one 128-col x 256-K fp8 B tile (32 KB) into LDS, async.
// LDS layout: byte(col, koff) = col*256 + (koff ^ ((col&15)<<4)) — XOR over
// bits [7:4] spans the FULL 256B row across 16 cols, making the b64 fragment
// reads conflict-free (the R6/R7 8-row swizzle left a 4-way conflict).
// global_load_lds writes linearly, so the SOURCE is inverse-swizzled (rule 21).
__device__ __forceinline__ void stage_tile(unsigned char* dst,
                                           const unsigned char* src_base,
                                           int col0, int wid, int lane) {
  const char* gb = (const char*)src_base + (size_t)col0 * 256;
  #pragma unroll
  for (int it = 0; it < 4; ++it) {
    int cb = it * 512 + wid * 64;        // wave-uniform chunk base (16B units)
    int ch = cb + lane;                  // 0..2047
    int cc = ch >> 4;                    // tile-local col 0..127
    int w  = (ch & 15) << 4;             // 16B block within the 256B row
    int src = cc * 256 + (w ^ ((cc & 15) << 4));
    __builtin_amdgcn_global_load_lds(
        (const __attribute__((address_space(1))) void*)(gb + src),
        (__attribute__((address_space(3))) void*)(dst + cb * 16),
        16, 0, 0);
  }
}

// one 256x128 tile: wave = 32 rows x 128 cols (mA=2 so A fits registers
// WITHIN the 128-reg budget alongside acc — ending the R3-R7 streaming war).
// Per K-step: 2 resident A frags x 8 LDS B-reads -> 16 MFMA (1.6:1 MFMA:LDS).
__device__ __forceinline__ void compute_tile(
    const unsigned char* Bt, const long (&av)[2][8], float (&rs)[8],
    int g, int c) {
  // per-lane swizzle is c<<4 for every col-fragment (since (j*16+c)&15 == c)
  const char* Bb = (const char*)Bt + (size_t)c * 256;
  f32x4 acc[2][8];
  const f32x4 zero = {0.f, 0.f, 0.f, 0.f};
  #pragma unroll
  for (int m = 0; m < 2; ++m)
    #pragma unroll
    for (int j = 0; j < 8; ++j) acc[m][j] = zero;

  #pragma unroll
  for (int ks = 0; ks < 8; ++ks) {
    int koff = (ks * 32 + g * 8) ^ (c << 4);
    const char* kp = Bb + koff;
    #pragma unroll
    for (int j = 0; j < 8; ++j) {
      long bv = *(const long*)(kp + j * 4096);   // ds_read_b64, imm offset
      acc[0][j] = __builtin_amdgcn_mfma_f32_16x16x32_fp8_fp8(av[0][ks], bv, acc[0][j], 0, 0, 0);
      acc[1][j] = __builtin_amdgcn_mfma_f32_16x16x32_fp8_fp8(av[1][ks], bv, acc[1][j], 0, 0, 0);
    }
  }

  // unit-norm inputs: score = acc. C layout: col = j*16+c, row = m*16+g*4+jj
  #pragma unroll
  for (int j = 0; j < 8; ++j)
    #pragma unroll
    for (int m = 0; m < 2; ++m)
      #pragma unroll
      for (int jj = 0; jj < 4; ++jj)
        rs[m * 4 + jj] += __expf(acc[m][j][jj]);
}

// 512 threads = 8 waves x 32 rows. launch_bounds(512,4): 128-VGPR budget;
// working set (av 32 + acc 64 + rs 8 + misc) fits. LDS 64 KB -> 2 blocks/CU.
__global__ __launch_bounds__(512, 4) void gemm_lse_kernel(
    const unsigned char* __restrict__ qf8, const unsigned char* __restrict__ rf8,
    float* __restrict__ row_sum) {
  __shared__ __attribute__((aligned(16))) unsigned char Bl[2][BCOLS * DDIM]; // 2 x 32 KB

  const int tid  = threadIdx.x;
  const int lane = tid & 63;
  const int wid  = tid >> 6;
  const int g = lane >> 4, c = lane & 15;
  const int row0  = blockIdx.x * BROWS;
  const int col00 = blockIdx.y * (NTILES * BCOLS);

  // issue stage of tile 0 first; latency hides under the A-register loads
  stage_tile(&Bl[0][0], rf8, col00, wid, lane);

  // A fragments -> registers (2 row-frags x 8 K-slices = 32 VGPR), read once
  long av[2][8];
  const char* Ab = (const char*)qf8;
  #pragma unroll
  for (int m = 0; m < 2; ++m) {
    size_t rb = (size_t)(row0 + wid * 32 + m * 16 + c) * 256;
    #pragma unroll
    for (int ks = 0; ks < 8; ++ks)
      av[m][ks] = *(const long*)(Ab + rb + ks * 32 + g * 8);
  }

  float rs[8];
  #pragma unroll
  for (int k = 0; k < 8; ++k) rs[k] = 0.0f;

  __syncthreads();   // tile 0 resident

  // 2-phase pipeline: issue stage(t+1) BEFORE compute(t); the single
  // __syncthreads per tile drains vmcnt AFTER compute so in-flight loads
  // hide under MFMA. Manual x2 unroll keeps buffer indices compile-time.
  for (int t = 0; t < NTILES; t += 2) {
    if (t + 1 < NTILES)
      stage_tile(&Bl[1][0], rf8, col00 + (t + 1) * BCOLS, wid, lane);
    compute_tile(&Bl[0][0], av, rs, g, c);
    __syncthreads();

    if (t + 2 < NTILES)
      stage_tile(&Bl[0][0], rf8, col00 + (t + 2) * BCOLS, wid, lane);
    compute_tile(&Bl[1][0], av, rs, g, c);
    __syncthreads();
  }

  // reduce the 16 column-lanes holding the same row, one atomic per row
  #pragma unroll
  for (int k = 0; k < 8; ++k) {
    float v = rs[k];
    v += __shfl_xor(v, 1);
    v += __shfl_xor(v, 2);
    v += __shfl_xor(v, 4);
    v += __shfl_xor(v, 8);
    if (c == 0) {
      int row = row0 + wid * 32 + (k >> 2) * 16 + g * 4 + (k & 3);
      atomicAdd(&row_sum[row], v);
    }
  }
}

__global__ __launch_bounds__(256) void finalize_kernel(
    const float* __restrict__ row_sum, const float* __restrict__ pos,
    float* __restrict__ out, int n) {
  int t = threadIdx.x;
  float s = 0.f;
  #pragma unroll 4
  for (int i = t; i < n; i += 256) s += __logf(row_sum[i]) - pos[i];
  #pragma unroll
  for (int m = 1; m < 64; m <<= 1) s += __shfl_xor(s, m);
  __shared__ float red[4];
  if ((t & 63) == 0) red[t >> 6] = s;
  __syncthreads();
  if (t == 0) out[0] = red[0] + red[1] + red[2] + red[3];  // -loss = sum(lse - pos)
}

extern "C" void kernel_launch(void* const* d_in, const int* in_sizes, int n_in,
                              void* d_out, int out_size, void* d_ws, size_t ws_size,
                              hipStream_t stream) {
  const float* q = (const float*)d_in[0];
  const float* r = (const float*)d_in[1];
  int n = in_sizes[0] / DDIM;  // 8192

  char* w = (char*)d_ws;
  size_t f8Bytes = (size_t)n * DDIM;
  unsigned char* qf8 = (unsigned char*)w;
  unsigned char* rf8 = (unsigned char*)(w + f8Bytes);
  float* pos     = (float*)(w + 2 * f8Bytes);
  float* row_sum = pos + n;

  prep_kernel<<<n / 4, 256, 0, stream>>>(q, r, qf8, rf8, pos, row_sum);

  dim3 grid(n / BROWS, n / (NTILES * BCOLS));   // 32 x 16 = 512 blocks (2/CU)
  gemm_lse_kernel<<<grid, 512, 0, stream>>>(qf8, rf8, row_sum);

  finalize_kernel<<<1, 256, 0, stream>>>(row_sum, pos, (float*)d_out, n);
}

// Round 9
// 51.715 us; speedup vs baseline: 1.0342x; 1.0323x over previous
//
#include <hip/hip_runtime.h>
#include <hip/hip_bf16.h>

#define DDIM   256   // K (feature dim)
#define BROWS  256   // block output rows (8 waves x 32 rows)
#define BCOLS  128   // B tile columns
#define NTILES   4   // B tiles per block -> 512 cols per chunk

typedef float f32x4 __attribute__((ext_vector_type(4)));

// pack 4 f32 -> 4 fp8 e4m3 bytes
__device__ __forceinline__ unsigned int pack4_fp8(float a0, float a1, float a2, float a3) {
  int v = __builtin_amdgcn_cvt_pk_fp8_f32(a0, a1, 0, false);   // bytes 0,1
  v = __builtin_amdgcn_cvt_pk_fp8_f32(a2, a3, v, true);        // bytes 2,3
  return (unsigned int)v;
}

// ---- prep: one wave per row; writes UNIT-NORM fp8 rows + exact f32 diag ----
__global__ __launch_bounds__(256) void prep_kernel(
    const float* __restrict__ q, const float* __restrict__ r,
    unsigned char* __restrict__ qf8, unsigned char* __restrict__ rf8,
    float* __restrict__ pos, float* __restrict__ row_sum) {
  int lane = threadIdx.x & 63, wave = threadIdx.x >> 6;
  int row = blockIdx.x * 4 + wave;
  size_t base = (size_t)row * DDIM + lane * 4;
  float4 qv = *(const float4*)(q + base);
  float4 rv = *(const float4*)(r + base);
  float qq = qv.x*qv.x + qv.y*qv.y + qv.z*qv.z + qv.w*qv.w;
  float rr = rv.x*rv.x + rv.y*rv.y + rv.z*rv.z + rv.w*rv.w;
  float qr = qv.x*rv.x + qv.y*rv.y + qv.z*rv.z + qv.w*rv.w;
  #pragma unroll
  for (int m = 1; m < 64; m <<= 1) {
    qq += __shfl_xor(qq, m);
    rr += __shfl_xor(rr, m);
    qr += __shfl_xor(qr, m);
  }
  float iq = 1.0f / sqrtf(qq);
  float ir = 1.0f / sqrtf(rr);
  unsigned int qp = pack4_fp8(qv.x*iq, qv.y*iq, qv.z*iq, qv.w*iq);
  unsigned int rp = pack4_fp8(rv.x*ir, rv.y*ir, rv.z*ir, rv.w*ir);
  *(unsigned int*)(qf8 + base) = qp;
  *(unsigned int*)(rf8 + base) = rp;
  if (lane == 0) {
    pos[row] = qr * iq * ir;   // exact f32 diagonal from raw inputs
    row_sum[row] = 0.0f;
  }
}

// stage one 128-col x 256-K fp8 B tile (32 KB) into LDS, async.
// LDS layout: byte(col, koff) = col*256 + (koff ^ ((col&15)<<4)).
// global_load_lds writes linearly, so the SOURCE is inverse-swizzled (rule 21).
__device__ __forceinline__ void stage_tile(unsigned char* dst,
                                           const unsigned char* src_base,
                                           int col0, int wid, int lane) {
  const char* gb = (const char*)src_base + (size_t)col0 * 256;
  #pragma unroll
  for (int it = 0; it < 4; ++it) {
    int cb = it * 512 + wid * 64;        // wave-uniform chunk base (16B units)
    int ch = cb + lane;                  // 0..2047
    int cc = ch >> 4;                    // tile-local col 0..127
    int w  = (ch & 15) << 4;             // 16B block within the 256B row
    int src = cc * 256 + (w ^ ((cc & 15) << 4));
    __builtin_amdgcn_global_load_lds(
        (const __attribute__((address_space(1))) void*)(gb + src),
        (__attribute__((address_space(3))) void*)(dst + cb * 16),
        16, 0, 0);
  }
}

// one 256x128 tile: wave = 32 rows x 128 cols. A (fp8) resident in registers
// (2 frags x 8 K-slices = 32 VGPR), B from LDS b64 reads. Per K-step:
// 8 ds_read_b64 -> 16 MFMA (1.6:1 MFMA:LDS at CU level).
__device__ __forceinline__ void compute_tile(
    const unsigned char* Bt, const long (&av)[2][8], float (&rs)[8],
    int g, int c) {
  // per-lane swizzle is c<<4 for every col-fragment (since (j*16+c)&15 == c)
  const char* Bb = (const char*)Bt + (size_t)c * 256;
  f32x4 acc[2][8];
  const f32x4 zero = {0.f, 0.f, 0.f, 0.f};
  #pragma unroll
  for (int m = 0; m < 2; ++m)
    #pragma unroll
    for (int j = 0; j < 8; ++j) acc[m][j] = zero;

  #pragma unroll
  for (int ks = 0; ks < 8; ++ks) {
    int koff = (ks * 32 + g * 8) ^ (c << 4);
    const char* kp = Bb + koff;
    #pragma unroll
    for (int j = 0; j < 8; ++j) {
      long bv = *(const long*)(kp + j * 4096);   // ds_read_b64, imm offset
      acc[0][j] = __builtin_amdgcn_mfma_f32_16x16x32_fp8_fp8(av[0][ks], bv, acc[0][j], 0, 0, 0);
      acc[1][j] = __builtin_amdgcn_mfma_f32_16x16x32_fp8_fp8(av[1][ks], bv, acc[1][j], 0, 0, 0);
    }
  }

  // unit-norm inputs: score = acc. C layout: col = j*16+c, row = m*16+g*4+jj
  #pragma unroll
  for (int j = 0; j < 8; ++j)
    #pragma unroll
    for (int m = 0; m < 2; ++m)
      #pragma unroll
      for (int jj = 0; jj < 4; ++jj)
        rs[m * 4 + jj] += __expf(acc[m][j][jj]);
}

// 512 threads = 8 waves x 32 rows. launch_bounds(512,2) -> 128-VGPR budget
// (R6-verified); working set av(32)+acc(64)+rs(8)+misc ~ 115 FITS, unlike
// R8's (512,4) which capped at 64 regs and spilled the accumulators
// (WRITE_SIZE 54 MB of scratch). LDS 64 KB -> 2 blocks/CU = 4 waves/SIMD,
// matching the 128-reg occupancy step exactly.
__global__ __launch_bounds__(512, 2) void gemm_lse_kernel(
    const unsigned char* __restrict__ qf8, const unsigned char* __restrict__ rf8,
    float* __restrict__ row_sum) {
  __shared__ __attribute__((aligned(16))) unsigned char Bl[2][BCOLS * DDIM]; // 2 x 32 KB

  const int tid  = threadIdx.x;
  const int lane = tid & 63;
  const int wid  = tid >> 6;
  const int g = lane >> 4, c = lane & 15;
  const int row0  = blockIdx.x * BROWS;
  const int col00 = blockIdx.y * (NTILES * BCOLS);

  // issue stage of tile 0 first; latency hides under the A-register loads
  stage_tile(&Bl[0][0], rf8, col00, wid, lane);

  // A fragments -> registers (2 row-frags x 8 K-slices = 32 VGPR), read once
  long av[2][8];
  const char* Ab = (const char*)qf8;
  #pragma unroll
  for (int m = 0; m < 2; ++m) {
    size_t rb = (size_t)(row0 + wid * 32 + m * 16 + c) * 256;
    #pragma unroll
    for (int ks = 0; ks < 8; ++ks)
      av[m][ks] = *(const long*)(Ab + rb + ks * 32 + g * 8);
  }

  float rs[8];
  #pragma unroll
  for (int k = 0; k < 8; ++k) rs[k] = 0.0f;

  __syncthreads();   // tile 0 resident

  // 2-phase pipeline: issue stage(t+1) BEFORE compute(t); the single
  // __syncthreads per tile drains vmcnt AFTER compute so in-flight loads
  // hide under MFMA. Manual x2 unroll keeps buffer indices compile-time.
  for (int t = 0; t < NTILES; t += 2) {
    if (t + 1 < NTILES)
      stage_tile(&Bl[1][0], rf8, col00 + (t + 1) * BCOLS, wid, lane);
    compute_tile(&Bl[0][0], av, rs, g, c);
    __syncthreads();

    if (t + 2 < NTILES)
      stage_tile(&Bl[0][0], rf8, col00 + (t + 2) * BCOLS, wid, lane);
    compute_tile(&Bl[1][0], av, rs, g, c);
    __syncthreads();
  }

  // reduce the 16 column-lanes holding the same row, one atomic per row
  #pragma unroll
  for (int k = 0; k < 8; ++k) {
    float v = rs[k];
    v += __shfl_xor(v, 1);
    v += __shfl_xor(v, 2);
    v += __shfl_xor(v, 4);
    v += __shfl_xor(v, 8);
    if (c == 0) {
      int row = row0 + wid * 32 + (k >> 2) * 16 + g * 4 + (k & 3);
      atomicAdd(&row_sum[row], v);
    }
  }
}

__global__ __launch_bounds__(256) void finalize_kernel(
    const float* __restrict__ row_sum, const float* __restrict__ pos,
    float* __restrict__ out, int n) {
  int t = threadIdx.x;
  float s = 0.f;
  #pragma unroll 4
  for (int i = t; i < n; i += 256) s += __logf(row_sum[i]) - pos[i];
  #pragma unroll
  for (int m = 1; m < 64; m <<= 1) s += __shfl_xor(s, m);
  __shared__ float red[4];
  if ((t & 63) == 0) red[t >> 6] = s;
  __syncthreads();
  if (t == 0) out[0] = red[0] + red[1] + red[2] + red[3];  // -loss = sum(lse - pos)
}

extern "C" void kernel_launch(void* const* d_in, const int* in_sizes, int n_in,
                              void* d_out, int out_size, void* d_ws, size_t ws_size,
                              hipStream_t stream) {
  const float* q = (const float*)d_in[0];
  const float* r = (const float*)d_in[1];
  int n = in_sizes[0] / DDIM;  // 8192

  char* w = (char*)d_ws;
  size_t f8Bytes = (size_t)n * DDIM;
  unsigned char* qf8 = (unsigned char*)w;
  unsigned char* rf8 = (unsigned char*)(w + f8Bytes);
  float* pos     = (float*)(w + 2 * f8Bytes);
  float* row_sum = pos + n;

  prep_kernel<<<n / 4, 256, 0, stream>>>(q, r, qf8, rf8, pos, row_sum);

  dim3 grid(n / BROWS, n / (NTILES * BCOLS));   // 32 x 16 = 512 blocks (2/CU)
  gemm_lse_kernel<<<grid, 512, 0, stream>>>(qf8, rf8, row_sum);

  finalize_kernel<<<1, 256, 0, stream>>>(row_sum, pos, (float*)d_out, n);
}